// Round 2
// baseline (730.525 us; speedup 1.0000x reference)
//
#include <hip/hip_runtime.h>
#include <hip/hip_bf16.h>
#include <math.h>

typedef __bf16 bf16;
typedef bf16 bf16x8 __attribute__((ext_vector_type(8)));
typedef float f32x4 __attribute__((ext_vector_type(4)));

// ---- problem constants ----
constexpr int BATCH = 64;
constexpr int CIN   = 2048;
constexpr int HIDN  = 2048;
constexpr int OUTN  = 256;
constexpr int LL    = 196;   // H*W
constexpr int LCAT  = 197;   // pooled + L
constexpr int P1V   = BATCH * LCAT;   // 12608 valid rows
constexpr int P1P   = 12672;          // padded to 99*128
// output offsets (in floats)
constexpr size_t O_ZG   = 0;
constexpr size_t O_OVAL = (size_t)BATCH * OUTN;                   // 16384
constexpr size_t O_ATT  = O_OVAL + (size_t)BATCH * OUTN * 32;     // 540672
constexpr size_t O_ATTR = O_ATT + (size_t)BATCH * OUTN * LL;      // 3751936

// ---- workspace layout (bytes) ----
constexpr size_t WS_XCAT = 0;                            // bf16 [12672][2048]
constexpr size_t WS_V2   = WS_XCAT;                      // bf16 [2048][2048] (alias; XCAT dead)
constexpr size_t WS_H2T  = WS_XCAT + (size_t)(16u<<20);  // bf16 [2048][2048]
constexpr size_t WS_HT   = 51904512;                     // bf16 [12672][2048]
constexpr size_t WS_Z    = WS_HT + 51904512;             // f32  [256][12672]
constexpr size_t WS_W1B  = WS_Z + 12976128;              // bf16
constexpr size_t WS_W2B  = WS_W1B + 8388608;
constexpr size_t WS_W1OB = WS_W2B + 1048576;
constexpr size_t WS_W2OB = WS_W1OB + 8388608;
constexpr size_t WS_NRM  = WS_W2OB + 1048576;
constexpr size_t WS_SUMS = WS_NRM + 50176;               // f32 [4][2048]
constexpr size_t WS_SC1  = WS_SUMS + 32768;
constexpr size_t WS_SH1  = WS_SC1 + 8192;
constexpr size_t WS_SC2  = WS_SH1 + 8192;
constexpr size_t WS_SH2  = WS_SC2 + 8192;

// async global->LDS, 16B per lane; LDS dest = uniform base + lane*16 (linear)
__device__ __forceinline__ void gload16(const bf16* g, bf16* l){
  __builtin_amdgcn_global_load_lds((const __attribute__((address_space(1))) void*)g,
                                   (__attribute__((address_space(3))) void*)l, 16, 0, 0);
}

// ======================= small utility kernels =======================
__global__ __launch_bounds__(256) void cast_k(const float* __restrict__ s, bf16* __restrict__ d, int n){
  int i = blockIdx.x * 256 + threadIdx.x;
  if (i < n) d[i] = (bf16)s[i];
}
__global__ __launch_bounds__(256) void zero_f32(float* p, int n){
  int i = blockIdx.x * 256 + threadIdx.x;
  if (i < n) p[i] = 0.f;
}
__global__ __launch_bounds__(256) void zero_b16(bf16* p, int n){
  int i = blockIdx.x * 256 + threadIdx.x;
  if (i < n) p[i] = (bf16)0.f;
}

// prep: transpose x (b,c,l) -> Xcat[p=b*197+1+l][c] bf16, pooled row at p=b*197
__global__ __launch_bounds__(256) void prep_k(const float* __restrict__ x, bf16* __restrict__ xcat){
  __shared__ float xs[64][201];   // stride 201: banks spread (9*cc+l)%32
  int b  = blockIdx.x >> 5;
  int cg = blockIdx.x & 31;
  int c0 = cg * 64;
  int t  = threadIdx.x;
  const float* xb = x + ((size_t)b * CIN + c0) * LL;
  #pragma unroll
  for (int i = 0; i < 16; i++){
    int idx = i * 256 + t;
    int cc = idx >> 6, q = idx & 63;
    if (q < 49){
      float4 v = *(const float4*)(xb + (size_t)cc * LL + q * 4);
      xs[cc][q*4+0] = v.x; xs[cc][q*4+1] = v.y; xs[cc][q*4+2] = v.z; xs[cc][q*4+3] = v.w;
    }
  }
  __syncthreads();
  if (t < 64){
    float s = 0.f;
    for (int l = 0; l < LL; l++) s += xs[t][l];
    xcat[(size_t)(b * LCAT) * CIN + c0 + t] = (bf16)(s * (1.f / (float)LL));
  }
  int lw = t >> 6, cc = t & 63;
  for (int i = 0; i < 49; i++){
    int l = i * 4 + lw;
    xcat[(size_t)(b * LCAT + 1 + l) * CIN + c0 + cc] = (bf16)xs[cc][l];
  }
}

// per-channel column sums; each block covers all 2048 cols (8/thread), a row-chunk
__global__ __launch_bounds__(256) void stats_k(const bf16* __restrict__ src, int rows, int rpg,
                                               float* __restrict__ sum, float* __restrict__ sumsq){
  int o  = threadIdx.x * 8;
  int r0 = blockIdx.x * rpg;
  int r1 = min(rows, r0 + rpg);
  float s[8] = {0.f,0.f,0.f,0.f,0.f,0.f,0.f,0.f};
  float q[8] = {0.f,0.f,0.f,0.f,0.f,0.f,0.f,0.f};
  for (int r = r0; r < r1; r++){
    bf16x8 v = *(const bf16x8*)(src + (size_t)r * 2048 + o);
    #pragma unroll
    for (int j = 0; j < 8; j++){ float f = (float)v[j]; s[j] += f; q[j] += f * f; }
  }
  #pragma unroll
  for (int j = 0; j < 8; j++){
    atomicAdd(&sum[o + j], s[j]);
    atomicAdd(&sumsq[o + j], q[j]);
  }
}

__global__ __launch_bounds__(256) void finalize_k(const float* __restrict__ sum, const float* __restrict__ sumsq,
                                                  const float* __restrict__ g, const float* __restrict__ b,
                                                  float n, float* __restrict__ scale, float* __restrict__ shift){
  int o = blockIdx.x * 256 + threadIdx.x;
  float mu  = sum[o] / n;
  float var = sumsq[o] / n - mu * mu;
  float sc  = g[o] / sqrtf(var + 1e-5f);
  scale[o] = sc;
  shift[o] = b[o] - mu * sc;
}

__global__ __launch_bounds__(256) void zg_k(const float* __restrict__ z, float* __restrict__ dout){
  int gidx = blockIdx.x * 256 + threadIdx.x;   // b*256 + c
  int b = gidx >> 8, c = gidx & 255;
  dout[O_ZG + gidx] = z[(size_t)c * P1P + b * LCAT];
}

__global__ __launch_bounds__(256) void nrm_k(const float* __restrict__ z, float* __restrict__ nrm){
  int b = blockIdx.x, t = threadIdx.x;
  if (t >= LL) return;
  float acc = 0.f;
  const float* zb = z + (size_t)b * LCAT + 1 + t;
  for (int c = 0; c < OUTN; c++){
    float v = zb[(size_t)c * P1P];
    acc += v * v;
  }
  nrm[b * LL + t] = sqrtf(acc);
}

__global__ __launch_bounds__(64) void softmax_k(const float* __restrict__ z, const float* __restrict__ nrm,
                                                float* __restrict__ dout){
  int bc = blockIdx.x;         // b*256 + c
  int b  = bc >> 8;
  int lane = threadIdx.x;
  const float* zr = z + (size_t)(bc & 255) * P1P + b * LCAT + 1;
  const float* nr = nrm + b * LL;
  float a[4];
  float mx = -1e30f;
  #pragma unroll
  for (int j = 0; j < 4; j++){
    int l = lane + j * 64;
    if (l < LL){
      float v = zr[l] / fmaxf(nr[l], 1e-12f);
      a[j] = v; mx = fmaxf(mx, v);
    } else a[j] = -1e30f;
  }
  #pragma unroll
  for (int s = 1; s < 64; s <<= 1) mx = fmaxf(mx, __shfl_xor(mx, s, 64));
  float sum = 0.f;
  #pragma unroll
  for (int j = 0; j < 4; j++){
    a[j] = (a[j] > -1e29f) ? expf(a[j] - mx) : 0.f;
    sum += a[j];
  }
  #pragma unroll
  for (int s = 1; s < 64; s <<= 1) sum += __shfl_xor(sum, s, 64);
  float inv = 1.f / sum;
  float* o1 = dout + O_ATT  + (size_t)bc * LL;
  float* o2 = dout + O_ATTR + (size_t)bc * LL;
  #pragma unroll
  for (int j = 0; j < 4; j++){
    int l = lane + j * 64;
    if (l < LL){ float r = a[j] * inv; o1[l] = r; o2[l] = r; }
  }
}

// ======================= unified NT MFMA GEMM =======================
// D[i][j] = sum_k P[i][k] * Q[j][k]; operands K-contiguous rows.
// CFG1: h  = Xcat(12672) x w1b(2048),  K=2048 -> hT bf16       [A,Q gload, XCD swz]
// CFG2: z  = w2b(256)    x bn_relu(hT)(12672), K=2048 -> z f32 [A gload, Q reg+BN]
// CFG3: h2 = v2(2048)    x w1ob(2048), K=2048 -> h2T bf16      [A,Q gload, XCD swz]
// CFG4: out= w2ob(256)   x bn_relu(h2T)(2048) -> d_out remap   [A gload, Q reg+BN]
// CFG5: v  = attn(32)    x x-rows(256), K=196 f32 -> v2 bf16   [reg-staged, f32 cvt]
template<int CFG>
__global__ __launch_bounds__(256)
void gemm_k(const void* __restrict__ Ap, const void* __restrict__ Qp, void* __restrict__ Cp,
            const float* __restrict__ sc, const float* __restrict__ sh)
{
  constexpr int BM  = (CFG==5) ? 32 : (CFG==4 ? 64 : 128);
  constexpr int BN  = (CFG==5) ? 256 : (CFG==4 ? 64 : 128);
  constexpr int WR  = (CFG==5) ? 1 : 2;
  constexpr int WC  = 4 / WR;
  constexpr int WTM = BM / WR, WTN = BN / WC;
  constexpr int FM  = WTM / 16, FN = WTN / 16;
  constexpr int KT  = (CFG==5) ? 4 : 32;
  constexpr bool F32S = (CFG==5);
  constexpr bool QBN  = (CFG==2) || (CFG==4);
  constexpr bool AGL  = !F32S;                  // A via global_load_lds
  constexpr bool QGL  = (CFG==1) || (CFG==3);   // Q via global_load_lds
  constexpr int LDA = F32S ? LL : 2048;
  constexpr int LDQ = F32S ? LL : 2048;
  constexpr int CA  = BM / 32;   // reg-stage iters == gload chunks per wave
  constexpr int CQ  = BN / 32;

  __shared__ bf16 Ps[BM * 64];
  __shared__ bf16 Qs[BN * 64];

  const int t = threadIdx.x;
  const int lane = t & 63;
  const int wid  = t >> 6;
  const int wr = wid / WC, wc = wid % WC;
  const int sw8 = ((lane & 7) ^ (lane >> 3)) * 8;   // inverse-swizzled source col (elems)

  size_t aBase = 0, qBase = 0;
  int mOff = 0, nOff = 0;
  if constexpr (CFG == 5){
    int bh = blockIdx.x;                       // b*8 + head
    aBase = (size_t)bh * 32 * LL;
    qBase = ((size_t)(bh >> 3) * 2048 + (size_t)(bh & 7) * 256) * LL;
    mOff = (bh >> 3) * 32;
    nOff = (bh & 7) * 256;
  } else if constexpr (CFG == 1){
    int bid = blockIdx.x;                      // 1584 = 99*16, %8==0
    int wg = (bid & 7) * 198 + (bid >> 3);     // bijective XCD swizzle
    mOff = (wg >> 4) * BM;  nOff = (wg & 15) * BN;
    aBase = (size_t)mOff * LDA; qBase = (size_t)nOff * LDQ;
  } else if constexpr (CFG == 3){
    int bid = blockIdx.x;                      // 256
    int wg = (bid & 7) * 32 + (bid >> 3);
    mOff = (wg >> 4) * BM;  nOff = (wg & 15) * BN;
    aBase = (size_t)mOff * LDA; qBase = (size_t)nOff * LDQ;
  } else {
    mOff = blockIdx.x * BM;
    nOff = blockIdx.y * BN;
    aBase = (size_t)mOff * LDA;
    qBase = (size_t)nOff * LDQ;
  }

  f32x4 acc[FM][FN] = {};

  for (int kt = 0; kt < KT; ++kt){
    const int k0 = kt * 64;
    bf16x8 ra[CA], rq[CQ];
    // ---- reg-stage global loads (current tile) ----
    if constexpr (!AGL){   // CFG5 A: f32 attn rows, float4 + tail guard
      #pragma unroll
      for (int i = 0; i < CA; i++){
        int ch = i * 256 + t;
        int row = ch >> 3, kc = ch & 7, kg = k0 + kc * 8;
        const float* g = (const float*)Ap + aBase + (size_t)row * LDA + kg;
        #pragma unroll
        for (int jj = 0; jj < 8; jj += 4){
          if (kg + jj + 3 < LL){
            float4 v = *(const float4*)(g + jj);
            ra[i][jj] = (bf16)v.x; ra[i][jj+1] = (bf16)v.y;
            ra[i][jj+2] = (bf16)v.z; ra[i][jj+3] = (bf16)v.w;
          } else {
            for (int j = jj; j < jj + 4; j++) ra[i][j] = (bf16)((kg + j) < LL ? g[j] : 0.f);
          }
        }
      }
    }
    if constexpr (!QGL){
      #pragma unroll
      for (int i = 0; i < CQ; i++){
        int ch = i * 256 + t;
        int row = ch >> 3, kc = ch & 7, kg = k0 + kc * 8;
        if constexpr (F32S){
          const float* g = (const float*)Qp + qBase + (size_t)row * LDQ + kg;
          #pragma unroll
          for (int jj = 0; jj < 8; jj += 4){
            if (kg + jj + 3 < LL){
              float4 v = *(const float4*)(g + jj);
              rq[i][jj] = (bf16)v.x; rq[i][jj+1] = (bf16)v.y;
              rq[i][jj+2] = (bf16)v.z; rq[i][jj+3] = (bf16)v.w;
            } else {
              for (int j = jj; j < jj + 4; j++) rq[i][j] = (bf16)((kg + j) < LL ? g[j] : 0.f);
            }
          }
        } else {  // QBN: bf16 + scale/shift + relu
          bf16x8 raw = *(const bf16x8*)((const bf16*)Qp + qBase + (size_t)row * LDQ + kg);
          #pragma unroll
          for (int j = 0; j < 8; j++){
            float f = (float)raw[j] * sc[kg + j] + sh[kg + j];
            rq[i][j] = (bf16)fmaxf(f, 0.f);
          }
        }
      }
    }
    __syncthreads();   // prev-iter readers done; LDS free to overwrite
    // ---- async global->LDS (linear dest, inverse-swizzled source) ----
    if constexpr (AGL){
      #pragma unroll
      for (int c = 0; c < CA; c++){
        int chunk = wid * CA + c;
        int row = chunk * 8 + (lane >> 3);
        gload16((const bf16*)Ap + aBase + (size_t)row * LDA + k0 + sw8, &Ps[chunk * 512]);
      }
    }
    if constexpr (QGL){
      #pragma unroll
      for (int c = 0; c < CQ; c++){
        int chunk = wid * CQ + c;
        int row = chunk * 8 + (lane >> 3);
        gload16((const bf16*)Qp + qBase + (size_t)row * LDQ + k0 + sw8, &Qs[chunk * 512]);
      }
    }
    // ---- reg-staged LDS writes (swizzled) ----
    if constexpr (!AGL){
      #pragma unroll
      for (int i = 0; i < CA; i++){
        int ch = i * 256 + t; int row = ch >> 3, kc = ch & 7;
        *(bf16x8*)&Ps[row * 64 + ((kc ^ (row & 7)) << 3)] = ra[i];
      }
    }
    if constexpr (!QGL){
      #pragma unroll
      for (int i = 0; i < CQ; i++){
        int ch = i * 256 + t; int row = ch >> 3, kc = ch & 7;
        *(bf16x8*)&Qs[row * 64 + ((kc ^ (row & 7)) << 3)] = rq[i];
      }
    }
    __syncthreads();   // drains vmcnt (gload) + lgkm (ds_write)
    // ---- compute ----
    #pragma unroll
    for (int ks = 0; ks < 2; ++ks){
      const int kcl = ks * 4 + (lane >> 4);
      bf16x8 af[FM], qf[FN];
      #pragma unroll
      for (int m = 0; m < FM; m++){
        int row = wr * WTM + m * 16 + (lane & 15);
        af[m] = *(const bf16x8*)&Ps[row * 64 + ((kcl ^ (row & 7)) << 3)];
      }
      #pragma unroll
      for (int n = 0; n < FN; n++){
        int row = wc * WTN + n * 16 + (lane & 15);
        qf[n] = *(const bf16x8*)&Qs[row * 64 + ((kcl ^ (row & 7)) << 3)];
      }
      #pragma unroll
      for (int m = 0; m < FM; m++)
        #pragma unroll
        for (int n = 0; n < FN; n++)
          acc[m][n] = __builtin_amdgcn_mfma_f32_16x16x32_bf16(af[m], qf[n], acc[m][n], 0, 0, 0);
    }
  }

  // epilogue: C/D map col = lane&15, row = (lane>>4)*4 + r
  #pragma unroll
  for (int m = 0; m < FM; m++){
    #pragma unroll
    for (int n = 0; n < FN; n++){
      #pragma unroll
      for (int r = 0; r < 4; r++){
        int row = mOff + wr * WTM + m * 16 + (lane >> 4) * 4 + r;
        int col = nOff + wc * WTN + n * 16 + (lane & 15);
        float v = acc[m][n][r];
        if constexpr (CFG == 1 || CFG == 3 || CFG == 5){
          ((bf16*)Cp)[(size_t)row * 2048 + col] = (bf16)v;
        } else if constexpr (CFG == 2){
          ((float*)Cp)[(size_t)row * P1P + col] = v;
        } else {  // CFG==4: d_out obj_val remap
          ((float*)Cp)[O_OVAL + (size_t)(col >> 5) * 8192 + (size_t)row * 32 + (col & 31)] = v;
        }
      }
    }
  }
}

// ======================= launch =======================
extern "C" void kernel_launch(void* const* d_in, const int* in_sizes, int n_in,
                              void* d_out, int out_size, void* d_ws, size_t ws_size,
                              hipStream_t stream){
  const float* x   = (const float*)d_in[0];
  const float* w1p = (const float*)d_in[1];
  const float* gp  = (const float*)d_in[2];
  const float* bp  = (const float*)d_in[3];
  const float* w2p = (const float*)d_in[4];
  const float* w1o = (const float*)d_in[5];
  const float* go  = (const float*)d_in[6];
  const float* bo  = (const float*)d_in[7];
  const float* w2o = (const float*)d_in[8];
  float* out = (float*)d_out;
  char* ws = (char*)d_ws;

  bf16* xcat = (bf16*)(ws + WS_XCAT);
  bf16* v2   = (bf16*)(ws + WS_V2);
  bf16* h2t  = (bf16*)(ws + WS_H2T);
  bf16* hT   = (bf16*)(ws + WS_HT);
  float* z   = (float*)(ws + WS_Z);
  bf16* w1b  = (bf16*)(ws + WS_W1B);
  bf16* w2b  = (bf16*)(ws + WS_W2B);
  bf16* w1ob = (bf16*)(ws + WS_W1OB);
  bf16* w2ob = (bf16*)(ws + WS_W2OB);
  float* nrmw = (float*)(ws + WS_NRM);
  float* sums = (float*)(ws + WS_SUMS);
  float* sc1 = (float*)(ws + WS_SC1);
  float* sh1 = (float*)(ws + WS_SH1);
  float* sc2 = (float*)(ws + WS_SC2);
  float* sh2 = (float*)(ws + WS_SH2);

  cast_k<<<16384, 256, 0, stream>>>(w1p, w1b, HIDN * CIN);
  cast_k<<<2048,  256, 0, stream>>>(w2p, w2b, OUTN * HIDN);
  cast_k<<<16384, 256, 0, stream>>>(w1o, w1ob, HIDN * CIN);
  cast_k<<<2048,  256, 0, stream>>>(w2o, w2ob, OUTN * HIDN);
  zero_f32<<<32, 256, 0, stream>>>(sums, 4 * 2048);
  zero_b16<<<512, 256, 0, stream>>>(xcat + (size_t)P1V * 2048, (P1P - P1V) * 2048);
  prep_k<<<2048, 256, 0, stream>>>(x, xcat);

  // MLP1
  gemm_k<1><<<1584, 256, 0, stream>>>(xcat, w1b, hT, nullptr, nullptr);
  stats_k<<<32, 256, 0, stream>>>(hT, P1V, 394, sums, sums + 2048);
  finalize_k<<<8, 256, 0, stream>>>(sums, sums + 2048, gp, bp, (float)P1V, sc1, sh1);
  gemm_k<2><<<dim3(2, 99), 256, 0, stream>>>(w2b, hT, z, sc1, sh1);

  // z_g, channel-norm, softmax
  zg_k<<<64, 256, 0, stream>>>(z, out);
  nrm_k<<<64, 256, 0, stream>>>(z, nrmw);
  softmax_k<<<16384, 64, 0, stream>>>(z, nrmw, out);

  // attention einsum -> MLP2
  gemm_k<5><<<512, 256, 0, stream>>>(out + O_ATT, x, v2, nullptr, nullptr);
  gemm_k<3><<<256, 256, 0, stream>>>(v2, w1ob, h2t, nullptr, nullptr);
  stats_k<<<8, 256, 0, stream>>>(h2t, 2048, 256, sums + 4096, sums + 6144);
  finalize_k<<<8, 256, 0, stream>>>(sums + 4096, sums + 6144, go, bo, 2048.f, sc2, sh2);
  gemm_k<4><<<dim3(4, 32), 256, 0, stream>>>(w2ob, h2t, out, sc2, sh2);
}

// Round 3
// 673.159 us; speedup vs baseline: 1.0852x; 1.0852x over previous
//
#include <hip/hip_runtime.h>
#include <hip/hip_bf16.h>
#include <math.h>

typedef __bf16 bf16;
typedef bf16 bf16x8 __attribute__((ext_vector_type(8)));
typedef float f32x4 __attribute__((ext_vector_type(4)));

// ---- problem constants ----
constexpr int BATCH = 64;
constexpr int CIN   = 2048;
constexpr int HIDN  = 2048;
constexpr int OUTN  = 256;
constexpr int LL    = 196;   // H*W
constexpr int LCAT  = 197;   // pooled + L
constexpr int P1V   = BATCH * LCAT;   // 12608 valid rows
constexpr int P1P   = 12672;          // padded to 99*128
// output offsets (in floats)
constexpr size_t O_ZG   = 0;
constexpr size_t O_OVAL = (size_t)BATCH * OUTN;                   // 16384
constexpr size_t O_ATT  = O_OVAL + (size_t)BATCH * OUTN * 32;     // 540672
constexpr size_t O_ATTR = O_ATT + (size_t)BATCH * OUTN * LL;      // 3751936

// ---- workspace layout (bytes) ----
constexpr size_t WS_XCAT = 0;                            // bf16 [12672][2048]
constexpr size_t WS_V2   = WS_XCAT;                      // bf16 [2048][2048] (alias; XCAT dead)
constexpr size_t WS_H2T  = WS_XCAT + (size_t)(16u<<20);  // bf16 [2048][2048]
constexpr size_t WS_PART = WS_XCAT + (size_t)(28u<<20);  // f32 [256][4096] partial stats (alias, dead zone)
constexpr size_t WS_HT   = 51904512;                     // bf16 [12672][2048]
constexpr size_t WS_Z    = WS_HT + 51904512;             // f32  [256][12672]
constexpr size_t WS_W1B  = WS_Z + 12976128;              // bf16
constexpr size_t WS_W2B  = WS_W1B + 8388608;
constexpr size_t WS_W1OB = WS_W2B + 1048576;
constexpr size_t WS_W2OB = WS_W1OB + 8388608;
constexpr size_t WS_NRM  = WS_W2OB + 1048576;
constexpr size_t WS_SC1  = WS_NRM + 50176;
constexpr size_t WS_SH1  = WS_SC1 + 8192;
constexpr size_t WS_SC2  = WS_SH1 + 8192;
constexpr size_t WS_SH2  = WS_SC2 + 8192;

// async global->LDS, 16B per lane; LDS dest = uniform base + lane*16 (linear)
__device__ __forceinline__ void gload16(const bf16* g, bf16* l){
  __builtin_amdgcn_global_load_lds((const __attribute__((address_space(1))) void*)g,
                                   (__attribute__((address_space(3))) void*)l, 16, 0, 0);
}

// ======================= small utility kernels =======================
__global__ __launch_bounds__(256) void cast_k(const float* __restrict__ s, bf16* __restrict__ d, int n){
  int i = blockIdx.x * 256 + threadIdx.x;
  if (i < n) d[i] = (bf16)s[i];
}
__global__ __launch_bounds__(256) void zero_b16(bf16* p, int n){
  int i = blockIdx.x * 256 + threadIdx.x;
  if (i < n) p[i] = (bf16)0.f;
}

// prep: transpose x (b,c,l) -> Xcat[p=b*197+1+l][c] bf16, pooled row at p=b*197
__global__ __launch_bounds__(256) void prep_k(const float* __restrict__ x, bf16* __restrict__ xcat){
  __shared__ float xs[64][201];   // stride 201 spreads banks
  int b  = blockIdx.x >> 5;
  int cg = blockIdx.x & 31;
  int c0 = cg * 64;
  int t  = threadIdx.x;
  const float* xb = x + ((size_t)b * CIN + c0) * LL;
  #pragma unroll
  for (int i = 0; i < 16; i++){
    int idx = i * 256 + t;
    int cc = idx >> 6, q = idx & 63;
    if (q < 49){
      float4 v = *(const float4*)(xb + (size_t)cc * LL + q * 4);
      xs[cc][q*4+0] = v.x; xs[cc][q*4+1] = v.y; xs[cc][q*4+2] = v.z; xs[cc][q*4+3] = v.w;
    }
  }
  __syncthreads();
  if (t < 64){
    float s = 0.f;
    for (int l = 0; l < LL; l++) s += xs[t][l];
    xcat[(size_t)(b * LCAT) * CIN + c0 + t] = (bf16)(s * (1.f / (float)LL));
  }
  // vectorized transpose-out: thread (lw=t>>3 row, cg8=t&7 8-col group)
  int lw = t >> 3, cg8 = t & 7;
  #pragma unroll
  for (int pass = 0; pass < 7; pass++){
    int l = pass * 32 + lw;
    if (l < LL){
      bf16x8 w;
      #pragma unroll
      for (int j = 0; j < 8; j++) w[j] = (bf16)xs[cg8 * 8 + j][l];
      *(bf16x8*)(xcat + (size_t)(b * LCAT + 1 + l) * CIN + c0 + cg8 * 8) = w;
    }
  }
}

// stage A: per-block partial column sums/sumsq over a row chunk -> part[blk][4096]
__global__ __launch_bounds__(256) void stats_part_k(const bf16* __restrict__ src, int rows, int rpg,
                                                    float* __restrict__ part){
  int o  = threadIdx.x * 8;
  int r0 = blockIdx.x * rpg;
  int r1 = min(rows, r0 + rpg);
  float s[8] = {0.f,0.f,0.f,0.f,0.f,0.f,0.f,0.f};
  float q[8] = {0.f,0.f,0.f,0.f,0.f,0.f,0.f,0.f};
  for (int r = r0; r < r1; r++){
    bf16x8 v = *(const bf16x8*)(src + (size_t)r * 2048 + o);
    #pragma unroll
    for (int j = 0; j < 8; j++){ float f = (float)v[j]; s[j] += f; q[j] += f * f; }
  }
  float* p = part + (size_t)blockIdx.x * 4096;
  #pragma unroll
  for (int j = 0; j < 8; j++){ p[o + j] = s[j]; p[2048 + o + j] = q[j]; }
}

// stage B: reduce partials + compute BN scale/shift
__global__ __launch_bounds__(256) void finalize_k(const float* __restrict__ part, int np,
                                                  const float* __restrict__ g, const float* __restrict__ b,
                                                  float n, float* __restrict__ scale, float* __restrict__ shift){
  int o = blockIdx.x * 256 + threadIdx.x;   // 0..2047
  float s = 0.f, q = 0.f;
  for (int p = 0; p < np; p++){
    s += part[(size_t)p * 4096 + o];
    q += part[(size_t)p * 4096 + 2048 + o];
  }
  float mu  = s / n;
  float var = q / n - mu * mu;
  float sc  = g[o] / sqrtf(var + 1e-5f);
  scale[o] = sc;
  shift[o] = b[o] - mu * sc;
}

__global__ __launch_bounds__(256) void zg_k(const float* __restrict__ z, float* __restrict__ dout){
  int gidx = blockIdx.x * 256 + threadIdx.x;   // b*256 + c
  int b = gidx >> 8, c = gidx & 255;
  dout[O_ZG + gidx] = z[(size_t)c * P1P + b * LCAT];
}

__global__ __launch_bounds__(256) void nrm_k(const float* __restrict__ z, float* __restrict__ nrm){
  int b = blockIdx.x, t = threadIdx.x;
  if (t >= LL) return;
  float acc = 0.f;
  const float* zb = z + (size_t)b * LCAT + 1 + t;
  for (int c = 0; c < OUTN; c++){
    float v = zb[(size_t)c * P1P];
    acc += v * v;
  }
  nrm[b * LL + t] = sqrtf(acc);
}

__global__ __launch_bounds__(64) void softmax_k(const float* __restrict__ z, const float* __restrict__ nrm,
                                                float* __restrict__ dout){
  int bc = blockIdx.x;         // b*256 + c
  int b  = bc >> 8;
  int lane = threadIdx.x;
  const float* zr = z + (size_t)(bc & 255) * P1P + b * LCAT + 1;
  const float* nr = nrm + b * LL;
  float a[4];
  float mx = -1e30f;
  #pragma unroll
  for (int j = 0; j < 4; j++){
    int l = lane + j * 64;
    if (l < LL){
      float v = zr[l] / fmaxf(nr[l], 1e-12f);
      a[j] = v; mx = fmaxf(mx, v);
    } else a[j] = -1e30f;
  }
  #pragma unroll
  for (int s = 1; s < 64; s <<= 1) mx = fmaxf(mx, __shfl_xor(mx, s, 64));
  float sum = 0.f;
  #pragma unroll
  for (int j = 0; j < 4; j++){
    a[j] = (a[j] > -1e29f) ? expf(a[j] - mx) : 0.f;
    sum += a[j];
  }
  #pragma unroll
  for (int s = 1; s < 64; s <<= 1) sum += __shfl_xor(sum, s, 64);
  float inv = 1.f / sum;
  float* o1 = dout + O_ATT  + (size_t)bc * LL;
  float* o2 = dout + O_ATTR + (size_t)bc * LL;
  #pragma unroll
  for (int j = 0; j < 4; j++){
    int l = lane + j * 64;
    if (l < LL){ float r = a[j] * inv; o1[l] = r; o2[l] = r; }
  }
}

// ======================= unified NT MFMA GEMM =======================
// D[i][j] = sum_k P[i][k] * Q[j][k]; operands K-contiguous rows.
// CFG1: h  = Xcat(12672) x w1b(2048),  K=2048 -> hT bf16       [A,Q gload, XCD swz]
// CFG2: z  = w2b(256)    x bn_relu(hT)(12672), K=2048 -> z f32 [A gload, Q reg+BN]
// CFG3: h2 = v2(2048)    x w1ob(2048), K=2048 -> h2T bf16      [A,Q gload, XCD swz]
// CFG4: out= w2ob(256)   x bn_relu(h2T)(2048) -> d_out remap   [A gload, Q reg+BN]
// CFG5: v  = attn(32)    x x-rows(256), K=196 f32 -> v2 bf16   [reg-staged, f32 cvt]
template<int CFG>
__global__ __launch_bounds__(256)
void gemm_k(const void* __restrict__ Ap, const void* __restrict__ Qp, void* __restrict__ Cp,
            const float* __restrict__ sc, const float* __restrict__ sh)
{
  constexpr int BM  = (CFG==5) ? 32 : (CFG==4 ? 64 : 128);
  constexpr int BN  = (CFG==5) ? 256 : (CFG==4 ? 64 : 128);
  constexpr int WR  = (CFG==5) ? 1 : 2;
  constexpr int WC  = 4 / WR;
  constexpr int WTM = BM / WR, WTN = BN / WC;
  constexpr int FM  = WTM / 16, FN = WTN / 16;
  constexpr int KT  = (CFG==5) ? 4 : 32;
  constexpr bool F32S = (CFG==5);
  constexpr bool QBN  = (CFG==2) || (CFG==4);
  constexpr bool AGL  = !F32S;                  // A via global_load_lds
  constexpr bool QGL  = (CFG==1) || (CFG==3);   // Q via global_load_lds
  constexpr int LDA = F32S ? LL : 2048;
  constexpr int LDQ = F32S ? LL : 2048;
  constexpr int CA  = BM / 32;
  constexpr int CQ  = BN / 32;

  __shared__ bf16 Ps[BM * 64];
  __shared__ bf16 Qs[BN * 64];

  const int t = threadIdx.x;
  const int lane = t & 63;
  const int wid  = t >> 6;
  const int wr = wid / WC, wc = wid % WC;
  const int sw8 = ((lane & 7) ^ (lane >> 3)) * 8;   // inverse-swizzled source col (elems)

  size_t aBase = 0, qBase = 0;
  int mOff = 0, nOff = 0;
  if constexpr (CFG == 5){
    int bh = blockIdx.x;                       // b*8 + head
    aBase = (size_t)bh * 32 * LL;
    qBase = ((size_t)(bh >> 3) * 2048 + (size_t)(bh & 7) * 256) * LL;
    mOff = (bh >> 3) * 32;
    nOff = (bh & 7) * 256;
  } else if constexpr (CFG == 1){
    int bid = blockIdx.x;                      // 1584 = 99*16, %8==0
    int wg = (bid & 7) * 198 + (bid >> 3);     // bijective XCD swizzle
    mOff = (wg >> 4) * BM;  nOff = (wg & 15) * BN;
    aBase = (size_t)mOff * LDA; qBase = (size_t)nOff * LDQ;
  } else if constexpr (CFG == 3){
    int bid = blockIdx.x;                      // 256
    int wg = (bid & 7) * 32 + (bid >> 3);
    mOff = (wg >> 4) * BM;  nOff = (wg & 15) * BN;
    aBase = (size_t)mOff * LDA; qBase = (size_t)nOff * LDQ;
  } else {
    mOff = blockIdx.x * BM;
    nOff = blockIdx.y * BN;
    aBase = (size_t)mOff * LDA;
    qBase = (size_t)nOff * LDQ;
  }

  f32x4 acc[FM][FN] = {};

  for (int kt = 0; kt < KT; ++kt){
    const int k0 = kt * 64;
    bf16x8 ra[CA], rq[CQ];
    // ---- reg-stage global loads (current tile) ----
    if constexpr (!AGL){   // CFG5 A: f32 attn rows, float4 + tail guard
      #pragma unroll
      for (int i = 0; i < CA; i++){
        int ch = i * 256 + t;
        int row = ch >> 3, kc = ch & 7, kg = k0 + kc * 8;
        const float* g = (const float*)Ap + aBase + (size_t)row * LDA + kg;
        #pragma unroll
        for (int jj = 0; jj < 8; jj += 4){
          if (kg + jj + 3 < LL){
            float4 v = *(const float4*)(g + jj);
            ra[i][jj] = (bf16)v.x; ra[i][jj+1] = (bf16)v.y;
            ra[i][jj+2] = (bf16)v.z; ra[i][jj+3] = (bf16)v.w;
          } else {
            for (int j = jj; j < jj + 4; j++) ra[i][j] = (bf16)((kg + j) < LL ? g[j] : 0.f);
          }
        }
      }
    }
    if constexpr (!QGL){
      #pragma unroll
      for (int i = 0; i < CQ; i++){
        int ch = i * 256 + t;
        int row = ch >> 3, kc = ch & 7, kg = k0 + kc * 8;
        if constexpr (F32S){
          const float* g = (const float*)Qp + qBase + (size_t)row * LDQ + kg;
          #pragma unroll
          for (int jj = 0; jj < 8; jj += 4){
            if (kg + jj + 3 < LL){
              float4 v = *(const float4*)(g + jj);
              rq[i][jj] = (bf16)v.x; rq[i][jj+1] = (bf16)v.y;
              rq[i][jj+2] = (bf16)v.z; rq[i][jj+3] = (bf16)v.w;
            } else {
              for (int j = jj; j < jj + 4; j++) rq[i][j] = (bf16)((kg + j) < LL ? g[j] : 0.f);
            }
          }
        } else {  // QBN: bf16 + scale/shift + relu
          bf16x8 raw = *(const bf16x8*)((const bf16*)Qp + qBase + (size_t)row * LDQ + kg);
          #pragma unroll
          for (int j = 0; j < 8; j++){
            float f = (float)raw[j] * sc[kg + j] + sh[kg + j];
            rq[i][j] = (bf16)fmaxf(f, 0.f);
          }
        }
      }
    }
    __syncthreads();   // prev-iter readers done; LDS free to overwrite
    // ---- async global->LDS (linear dest, inverse-swizzled source) ----
    if constexpr (AGL){
      #pragma unroll
      for (int c = 0; c < CA; c++){
        int chunk = wid * CA + c;
        int row = chunk * 8 + (lane >> 3);
        gload16((const bf16*)Ap + aBase + (size_t)row * LDA + k0 + sw8, &Ps[chunk * 512]);
      }
    }
    if constexpr (QGL){
      #pragma unroll
      for (int c = 0; c < CQ; c++){
        int chunk = wid * CQ + c;
        int row = chunk * 8 + (lane >> 3);
        gload16((const bf16*)Qp + qBase + (size_t)row * LDQ + k0 + sw8, &Qs[chunk * 512]);
      }
    }
    // ---- reg-staged LDS writes (swizzled) ----
    if constexpr (!AGL){
      #pragma unroll
      for (int i = 0; i < CA; i++){
        int ch = i * 256 + t; int row = ch >> 3, kc = ch & 7;
        *(bf16x8*)&Ps[row * 64 + ((kc ^ (row & 7)) << 3)] = ra[i];
      }
    }
    if constexpr (!QGL){
      #pragma unroll
      for (int i = 0; i < CQ; i++){
        int ch = i * 256 + t; int row = ch >> 3, kc = ch & 7;
        *(bf16x8*)&Qs[row * 64 + ((kc ^ (row & 7)) << 3)] = rq[i];
      }
    }
    __syncthreads();   // drains vmcnt (gload) + lgkm (ds_write)
    // ---- compute ----
    #pragma unroll
    for (int ks = 0; ks < 2; ++ks){
      const int kcl = ks * 4 + (lane >> 4);
      bf16x8 af[FM], qf[FN];
      #pragma unroll
      for (int m = 0; m < FM; m++){
        int row = wr * WTM + m * 16 + (lane & 15);
        af[m] = *(const bf16x8*)&Ps[row * 64 + ((kcl ^ (row & 7)) << 3)];
      }
      #pragma unroll
      for (int n = 0; n < FN; n++){
        int row = wc * WTN + n * 16 + (lane & 15);
        qf[n] = *(const bf16x8*)&Qs[row * 64 + ((kcl ^ (row & 7)) << 3)];
      }
      #pragma unroll
      for (int m = 0; m < FM; m++)
        #pragma unroll
        for (int n = 0; n < FN; n++)
          acc[m][n] = __builtin_amdgcn_mfma_f32_16x16x32_bf16(af[m], qf[n], acc[m][n], 0, 0, 0);
    }
  }

  // epilogue: C/D map col = lane&15, row = (lane>>4)*4 + r
  #pragma unroll
  for (int m = 0; m < FM; m++){
    #pragma unroll
    for (int n = 0; n < FN; n++){
      #pragma unroll
      for (int r = 0; r < 4; r++){
        int row = mOff + wr * WTM + m * 16 + (lane >> 4) * 4 + r;
        int col = nOff + wc * WTN + n * 16 + (lane & 15);
        float v = acc[m][n][r];
        if constexpr (CFG == 1 || CFG == 3 || CFG == 5){
          ((bf16*)Cp)[(size_t)row * 2048 + col] = (bf16)v;
        } else if constexpr (CFG == 2){
          ((float*)Cp)[(size_t)row * P1P + col] = v;
        } else {  // CFG==4: d_out obj_val remap
          ((float*)Cp)[O_OVAL + (size_t)(col >> 5) * 8192 + (size_t)row * 32 + (col & 31)] = v;
        }
      }
    }
  }
}

// ======================= launch =======================
extern "C" void kernel_launch(void* const* d_in, const int* in_sizes, int n_in,
                              void* d_out, int out_size, void* d_ws, size_t ws_size,
                              hipStream_t stream){
  const float* x   = (const float*)d_in[0];
  const float* w1p = (const float*)d_in[1];
  const float* gp  = (const float*)d_in[2];
  const float* bp  = (const float*)d_in[3];
  const float* w2p = (const float*)d_in[4];
  const float* w1o = (const float*)d_in[5];
  const float* go  = (const float*)d_in[6];
  const float* bo  = (const float*)d_in[7];
  const float* w2o = (const float*)d_in[8];
  float* out = (float*)d_out;
  char* ws = (char*)d_ws;

  bf16* xcat = (bf16*)(ws + WS_XCAT);
  bf16* v2   = (bf16*)(ws + WS_V2);
  bf16* h2t  = (bf16*)(ws + WS_H2T);
  float* part = (float*)(ws + WS_PART);
  bf16* hT   = (bf16*)(ws + WS_HT);
  float* z   = (float*)(ws + WS_Z);
  bf16* w1b  = (bf16*)(ws + WS_W1B);
  bf16* w2b  = (bf16*)(ws + WS_W2B);
  bf16* w1ob = (bf16*)(ws + WS_W1OB);
  bf16* w2ob = (bf16*)(ws + WS_W2OB);
  float* nrmw = (float*)(ws + WS_NRM);
  float* sc1 = (float*)(ws + WS_SC1);
  float* sh1 = (float*)(ws + WS_SH1);
  float* sc2 = (float*)(ws + WS_SC2);
  float* sh2 = (float*)(ws + WS_SH2);

  cast_k<<<16384, 256, 0, stream>>>(w1p, w1b, HIDN * CIN);
  cast_k<<<2048,  256, 0, stream>>>(w2p, w2b, OUTN * HIDN);
  cast_k<<<16384, 256, 0, stream>>>(w1o, w1ob, HIDN * CIN);
  cast_k<<<2048,  256, 0, stream>>>(w2o, w2ob, OUTN * HIDN);
  zero_b16<<<512, 256, 0, stream>>>(xcat + (size_t)P1V * 2048, (P1P - P1V) * 2048);
  prep_k<<<2048, 256, 0, stream>>>(x, xcat);

  // MLP1
  gemm_k<1><<<1584, 256, 0, stream>>>(xcat, w1b, hT, nullptr, nullptr);
  stats_part_k<<<256, 256, 0, stream>>>(hT, P1V, 50, part);
  finalize_k<<<8, 256, 0, stream>>>(part, 256, gp, bp, (float)P1V, sc1, sh1);
  gemm_k<2><<<dim3(2, 99), 256, 0, stream>>>(w2b, hT, z, sc1, sh1);

  // z_g, channel-norm, softmax
  zg_k<<<64, 256, 0, stream>>>(z, out);
  nrm_k<<<64, 256, 0, stream>>>(z, nrmw);
  softmax_k<<<16384, 64, 0, stream>>>(z, nrmw, out);

  // attention einsum -> MLP2
  gemm_k<5><<<512, 256, 0, stream>>>(out + O_ATT, x, v2, nullptr, nullptr);
  gemm_k<3><<<256, 256, 0, stream>>>(v2, w1ob, h2t, nullptr, nullptr);
  stats_part_k<<<64, 256, 0, stream>>>(h2t, 2048, 32, part);
  finalize_k<<<8, 256, 0, stream>>>(part, 64, go, bo, 2048.f, sc2, sh2);
  gemm_k<4><<<dim3(4, 32), 256, 0, stream>>>(w2ob, h2t, out, sc2, sh2);
}

// Round 4
// 656.634 us; speedup vs baseline: 1.1125x; 1.0252x over previous
//
#include <hip/hip_runtime.h>
#include <hip/hip_bf16.h>
#include <math.h>

typedef __bf16 bf16;
typedef bf16 bf16x8 __attribute__((ext_vector_type(8)));
typedef float f32x4 __attribute__((ext_vector_type(4)));

// ---- problem constants ----
constexpr int BATCH = 64;
constexpr int CIN   = 2048;
constexpr int HIDN  = 2048;
constexpr int OUTN  = 256;
constexpr int LL    = 196;   // H*W
constexpr int LCAT  = 197;   // pooled + L
constexpr int P1V   = BATCH * LCAT;   // 12608 valid rows
constexpr int P1P   = 12800;          // padded to 50*256 (8-phase 256-tile M)
// output offsets (in floats)
constexpr size_t O_ZG   = 0;
constexpr size_t O_OVAL = (size_t)BATCH * OUTN;                   // 16384
constexpr size_t O_ATT  = O_OVAL + (size_t)BATCH * OUTN * 32;     // 540672
constexpr size_t O_ATTR = O_ATT + (size_t)BATCH * OUTN * LL;      // 3751936

// ---- workspace layout (bytes) ----
constexpr size_t WS_XCAT = 0;                            // bf16 [12800][2048] = 52,428,800
constexpr size_t WS_V2   = WS_XCAT;                      // bf16 [2048][2048] (alias; XCAT dead)
constexpr size_t WS_H2T  = WS_XCAT + (size_t)(16u<<20);  // bf16 [2048][2048]
constexpr size_t WS_PART = WS_XCAT + (size_t)(28u<<20);  // f32 [256][4096] partial stats
constexpr size_t WS_HT   = 52428800;                     // bf16 [12800][2048]
constexpr size_t WS_Z    = 104857600;                    // f32  [256][12800]
constexpr size_t WS_W1B  = 117964800;
constexpr size_t WS_W2B  = 126353408;
constexpr size_t WS_W1OB = 127401984;
constexpr size_t WS_W2OB = 135790592;
constexpr size_t WS_NRM  = 136839168;
constexpr size_t WS_SC1  = 136889344;
constexpr size_t WS_SH1  = 136897536;
constexpr size_t WS_SC2  = 136905728;
constexpr size_t WS_SH2  = 136913920;

// async global->LDS, 16B per lane; LDS dest = uniform base + lane*16 (linear)
__device__ __forceinline__ void gload16(const bf16* g, bf16* l){
  __builtin_amdgcn_global_load_lds((const __attribute__((address_space(1))) void*)g,
                                   (__attribute__((address_space(3))) void*)l, 16, 0, 0);
}
// raw barrier with compiler-reorder fences (no implicit vmcnt(0) drain)
__device__ __forceinline__ void wgb(){
  asm volatile("" ::: "memory");
  __builtin_amdgcn_s_barrier();
  asm volatile("" ::: "memory");
}

// ======================= small utility kernels =======================
__global__ __launch_bounds__(256) void cast_k(const float* __restrict__ s, bf16* __restrict__ d, int n){
  int i = blockIdx.x * 256 + threadIdx.x;
  if (i < n) d[i] = (bf16)s[i];
}
__global__ __launch_bounds__(256) void zero_b16(bf16* p, int n){
  int i = blockIdx.x * 256 + threadIdx.x;
  if (i < n) p[i] = (bf16)0.f;
}

// prep: transpose x (b,c,l) -> Xcat[p=b*197+1+l][c] bf16, pooled row at p=b*197
__global__ __launch_bounds__(256) void prep_k(const float* __restrict__ x, bf16* __restrict__ xcat){
  __shared__ float xs[64][201];
  int b  = blockIdx.x >> 5;
  int cg = blockIdx.x & 31;
  int c0 = cg * 64;
  int t  = threadIdx.x;
  const float* xb = x + ((size_t)b * CIN + c0) * LL;
  #pragma unroll
  for (int i = 0; i < 16; i++){
    int idx = i * 256 + t;
    int cc = idx >> 6, q = idx & 63;
    if (q < 49){
      float4 v = *(const float4*)(xb + (size_t)cc * LL + q * 4);
      xs[cc][q*4+0] = v.x; xs[cc][q*4+1] = v.y; xs[cc][q*4+2] = v.z; xs[cc][q*4+3] = v.w;
    }
  }
  __syncthreads();
  if (t < 64){
    float s = 0.f;
    for (int l = 0; l < LL; l++) s += xs[t][l];
    xcat[(size_t)(b * LCAT) * CIN + c0 + t] = (bf16)(s * (1.f / (float)LL));
  }
  int lw = t >> 3, cg8 = t & 7;
  #pragma unroll
  for (int pass = 0; pass < 7; pass++){
    int l = pass * 32 + lw;
    if (l < LL){
      bf16x8 w;
      #pragma unroll
      for (int j = 0; j < 8; j++) w[j] = (bf16)xs[cg8 * 8 + j][l];
      *(bf16x8*)(xcat + (size_t)(b * LCAT + 1 + l) * CIN + c0 + cg8 * 8) = w;
    }
  }
}

// stage A: per-block partial column sums/sumsq over a row chunk -> part[blk][4096]
__global__ __launch_bounds__(256) void stats_part_k(const bf16* __restrict__ src, int rows, int rpg,
                                                    float* __restrict__ part){
  int o  = threadIdx.x * 8;
  int r0 = blockIdx.x * rpg;
  int r1 = min(rows, r0 + rpg);
  float s[8] = {0.f,0.f,0.f,0.f,0.f,0.f,0.f,0.f};
  float q[8] = {0.f,0.f,0.f,0.f,0.f,0.f,0.f,0.f};
  for (int r = r0; r < r1; r++){
    bf16x8 v = *(const bf16x8*)(src + (size_t)r * 2048 + o);
    #pragma unroll
    for (int j = 0; j < 8; j++){ float f = (float)v[j]; s[j] += f; q[j] += f * f; }
  }
  float* p = part + (size_t)blockIdx.x * 4096;
  #pragma unroll
  for (int j = 0; j < 8; j++){ p[o + j] = s[j]; p[2048 + o + j] = q[j]; }
}

__global__ __launch_bounds__(256) void finalize_k(const float* __restrict__ part, int np,
                                                  const float* __restrict__ g, const float* __restrict__ b,
                                                  float n, float* __restrict__ scale, float* __restrict__ shift){
  int o = blockIdx.x * 256 + threadIdx.x;
  float s = 0.f, q = 0.f;
  for (int p = 0; p < np; p++){
    s += part[(size_t)p * 4096 + o];
    q += part[(size_t)p * 4096 + 2048 + o];
  }
  float mu  = s / n;
  float var = q / n - mu * mu;
  float sc  = g[o] / sqrtf(var + 1e-5f);
  scale[o] = sc;
  shift[o] = b[o] - mu * sc;
}

__global__ __launch_bounds__(256) void zg_k(const float* __restrict__ z, float* __restrict__ dout){
  int gidx = blockIdx.x * 256 + threadIdx.x;
  int b = gidx >> 8, c = gidx & 255;
  dout[O_ZG + gidx] = z[(size_t)c * P1P + b * LCAT];
}

__global__ __launch_bounds__(256) void nrm_k(const float* __restrict__ z, float* __restrict__ nrm){
  int b = blockIdx.x, t = threadIdx.x;
  if (t >= LL) return;
  float acc = 0.f;
  const float* zb = z + (size_t)b * LCAT + 1 + t;
  for (int c = 0; c < OUTN; c++){
    float v = zb[(size_t)c * P1P];
    acc += v * v;
  }
  nrm[b * LL + t] = sqrtf(acc);
}

__global__ __launch_bounds__(64) void softmax_k(const float* __restrict__ z, const float* __restrict__ nrm,
                                                float* __restrict__ dout){
  int bc = blockIdx.x;
  int b  = bc >> 8;
  int lane = threadIdx.x;
  const float* zr = z + (size_t)(bc & 255) * P1P + b * LCAT + 1;
  const float* nr = nrm + b * LL;
  float a[4];
  float mx = -1e30f;
  #pragma unroll
  for (int j = 0; j < 4; j++){
    int l = lane + j * 64;
    if (l < LL){
      float v = zr[l] / fmaxf(nr[l], 1e-12f);
      a[j] = v; mx = fmaxf(mx, v);
    } else a[j] = -1e30f;
  }
  #pragma unroll
  for (int s = 1; s < 64; s <<= 1) mx = fmaxf(mx, __shfl_xor(mx, s, 64));
  float sum = 0.f;
  #pragma unroll
  for (int j = 0; j < 4; j++){
    a[j] = (a[j] > -1e29f) ? expf(a[j] - mx) : 0.f;
    sum += a[j];
  }
  #pragma unroll
  for (int s = 1; s < 64; s <<= 1) sum += __shfl_xor(sum, s, 64);
  float inv = 1.f / sum;
  float* o1 = dout + O_ATT  + (size_t)bc * LL;
  float* o2 = dout + O_ATTR + (size_t)bc * LL;
  #pragma unroll
  for (int j = 0; j < 4; j++){
    int l = lane + j * 64;
    if (l < LL){ float r = a[j] * inv; o1[l] = r; o2[l] = r; }
  }
}

// ======================= 8-phase 256x256 GEMM1 (T2+T3+T4+T5) =======================
// hT[12800][2048] = Xcat[12800][2048] x w1b[2048][2048]^T(NT), K=2048.
// 512 thr / 8 waves (2x4), BK=64, dbuf LDS 128KiB, counted vmcnt(4) at p4/p8.

template<int MBASE, int NB>
__device__ __forceinline__ void mfma_quad(const bf16x8 (&af)[2][4], const bf16x8 (&bf)[2][2],
                                          f32x4 (&acc)[8][4]){
  __builtin_amdgcn_s_setprio(1);
  #pragma unroll
  for (int ks = 0; ks < 2; ks++)
    #pragma unroll
    for (int j = 0; j < 4; j++)
      #pragma unroll
      for (int jj = 0; jj < 2; jj++)
        acc[MBASE+j][NB+jj] = __builtin_amdgcn_mfma_f32_16x16x32_bf16(af[ks][j], bf[ks][jj],
                                                                      acc[MBASE+j][NB+jj], 0, 0, 0);
  __builtin_amdgcn_s_setprio(0);
}
template<int MSET>
__device__ __forceinline__ void read_afr(const bf16* Ab, int wr, const int (&offk)[2], bf16x8 (&af)[2][4]){
  #pragma unroll
  for (int ks = 0; ks < 2; ks++)
    #pragma unroll
    for (int j = 0; j < 4; j++)
      af[ks][j] = *(const bf16x8*)(Ab + (wr*128 + (MSET*4+j)*16)*64 + offk[ks]);
}
template<int NB>
__device__ __forceinline__ void read_bfr(const bf16* Bb, int wc, const int (&offk)[2], bf16x8 (&bf)[2][2]){
  #pragma unroll
  for (int ks = 0; ks < 2; ks++)
    #pragma unroll
    for (int jj = 0; jj < 2; jj++)
      bf[ks][jj] = *(const bf16x8*)(Bb + (wc*64 + (NB+jj)*16)*64 + offk[ks]);
}

__global__ __launch_bounds__(512, 2)
void gemm1_k(const bf16* __restrict__ A, const bf16* __restrict__ B, bf16* __restrict__ C){
  constexpr int ATI = 256 * 64;          // elems per K-tile buffer (32 KiB)
  __shared__ bf16 As[2 * ATI];
  __shared__ bf16 Bs[2 * ATI];
  const int t = threadIdx.x, lane = t & 63, wid = t >> 6;
  const int wr = wid >> 2, wc = wid & 3;
  const int sw8 = ((lane & 7) ^ (lane >> 3)) * 8;
  int bid = blockIdx.x;                  // 400 = 50*8, %8==0
  int wg  = (bid & 7) * 50 + (bid >> 3); // XCD swizzle (bijective)
  const int mOff = (wg >> 3) * 256, nOff = (wg & 7) * 256;
  int offk[2];
  #pragma unroll
  for (int ks = 0; ks < 2; ks++) offk[ks] = (lane & 15) * 64 + (((ks*4 + (lane >> 4)) ^ (lane & 7)) << 3);

  f32x4 acc[8][4] = {};
  bf16x8 afr0[2][4], afr1[2][4], bfr0[2][2], bfr1[2][2];

  auto stage = [&](const bf16* __restrict__ G, int rbase, bf16* lds, int kt, int h){
    #pragma unroll
    for (int c = 0; c < 2; c++){
      int chunk = h * 16 + wid * 2 + c;
      int row = chunk * 8 + (lane >> 3);
      gload16(G + (size_t)(rbase + row) * 2048 + kt * 64 + sw8, lds + chunk * 512);
    }
  };

  // prologue: tile0 full (par0) + tile1 A halves (par1); vmcnt(4) => tile0 landed
  stage(A, mOff, As, 0, 0);        stage(A, mOff, As, 0, 1);
  stage(B, nOff, Bs, 0, 0);        stage(B, nOff, Bs, 0, 1);
  stage(A, mOff, As + ATI, 1, 0);  stage(A, mOff, As + ATI, 1, 1);
  asm volatile("s_waitcnt vmcnt(4)" ::: "memory");
  wgb();

  for (int i = 0; i < 16; i++){
    const int te = 2*i, to = 2*i + 1;
    const bool PRE = (i < 15);
    // p1: tile te quadrant (m0-3, n0-1); issue (to).B0
    read_afr<0>(As, wr, offk, afr0);  read_bfr<0>(Bs, wc, offk, bfr0);
    stage(B, nOff, Bs + ATI, to, 0);
    wgb();  mfma_quad<0,0>(afr0, bfr0, acc);  wgb();
    // p2: (m4-7, n0-1); issue (to).B1
    read_afr<1>(As, wr, offk, afr1);
    stage(B, nOff, Bs + ATI, to, 1);
    wgb();  mfma_quad<4,0>(afr1, bfr0, acc);  wgb();
    // p3: (m4-7, n2-3); issue (te+2).A0  [par0 A last read p2]
    read_bfr<2>(Bs, wc, offk, bfr1);
    if (PRE) stage(A, mOff, As, te + 2, 0);
    wgb();  mfma_quad<4,2>(afr1, bfr1, acc);  wgb();
    // p4: (m0-3, n2-3); issue (te+2).A1; vmcnt => tile to fully landed
    if (PRE){ stage(A, mOff, As, te + 2, 1); asm volatile("s_waitcnt vmcnt(4)" ::: "memory"); }
    else    { asm volatile("s_waitcnt vmcnt(0)" ::: "memory"); }
    wgb();  mfma_quad<0,2>(afr0, bfr1, acc);  wgb();
    // p5: tile to (par1) quadrant (m0-3, n0-1); issue (te+2).B0 [par0 B last read p3]
    read_afr<0>(As + ATI, wr, offk, afr0);  read_bfr<0>(Bs + ATI, wc, offk, bfr0);
    if (PRE) stage(B, nOff, Bs, te + 2, 0);
    wgb();  mfma_quad<0,0>(afr0, bfr0, acc);  wgb();
    // p6: (m4-7, n0-1); issue (te+2).B1
    read_afr<1>(As + ATI, wr, offk, afr1);
    if (PRE) stage(B, nOff, Bs, te + 2, 1);
    wgb();  mfma_quad<4,0>(afr1, bfr0, acc);  wgb();
    // p7: (m4-7, n2-3); issue (to+2).A0 [par1 A last read p6]
    read_bfr<2>(Bs + ATI, wc, offk, bfr1);
    if (PRE) stage(A, mOff, As + ATI, to + 2, 0);
    wgb();  mfma_quad<4,2>(afr1, bfr1, acc);  wgb();
    // p8: (m0-3, n2-3); issue (to+2).A1; vmcnt => tile te+2 fully landed
    if (PRE){ stage(A, mOff, As + ATI, to + 2, 1); asm volatile("s_waitcnt vmcnt(4)" ::: "memory"); }
    wgb();  mfma_quad<0,2>(afr0, bfr1, acc);  wgb();
  }

  // epilogue: C/D map col = lane&15, row = (lane>>4)*4 + r
  #pragma unroll
  for (int m = 0; m < 8; m++)
    #pragma unroll
    for (int n = 0; n < 4; n++)
      #pragma unroll
      for (int r = 0; r < 4; r++){
        int row = mOff + wr*128 + m*16 + (lane >> 4)*4 + r;
        int col = nOff + wc*64  + n*16 + (lane & 15);
        C[(size_t)row * 2048 + col] = (bf16)acc[m][n][r];
      }
}

// ======================= unified NT MFMA GEMM (2-phase, CFG 2/3/4/5) =======================
template<int CFG>
__device__ __forceinline__
void gemm_body(const void* __restrict__ Ap, const void* __restrict__ Qp, void* __restrict__ Cp,
               const float* __restrict__ sc, const float* __restrict__ sh)
{
  constexpr int BM  = (CFG==5) ? 32 : (CFG==4 ? 64 : 128);
  constexpr int BN  = (CFG==5) ? 256 : (CFG==4 ? 64 : 128);
  constexpr int WR  = (CFG==5) ? 1 : 2;
  constexpr int WC  = 4 / WR;
  constexpr int WTM = BM / WR, WTN = BN / WC;
  constexpr int FM  = WTM / 16, FN = WTN / 16;
  constexpr int KT  = (CFG==5) ? 4 : 32;
  constexpr bool F32S = (CFG==5);
  constexpr bool QBN  = (CFG==2) || (CFG==4);
  constexpr bool AGL  = !F32S;
  constexpr bool QGL  = (CFG==3);
  constexpr int LDA = F32S ? LL : 2048;
  constexpr int LDQ = F32S ? LL : 2048;
  constexpr int CA  = BM / 32;
  constexpr int CQ  = BN / 32;

  __shared__ bf16 Ps[BM * 64];
  __shared__ bf16 Qs[BN * 64];

  const int t = threadIdx.x;
  const int lane = t & 63;
  const int wid  = t >> 6;
  const int wr = wid / WC, wc = wid % WC;
  const int sw8 = ((lane & 7) ^ (lane >> 3)) * 8;

  size_t aBase = 0, qBase = 0;
  int mOff = 0, nOff = 0;
  if constexpr (CFG == 5){
    int bh = blockIdx.x;
    aBase = (size_t)bh * 32 * LL;
    qBase = ((size_t)(bh >> 3) * 2048 + (size_t)(bh & 7) * 256) * LL;
    mOff = (bh >> 3) * 32;
    nOff = (bh & 7) * 256;
  } else if constexpr (CFG == 3){
    int bid = blockIdx.x;                      // 256
    int wg = (bid & 7) * 32 + (bid >> 3);
    mOff = (wg >> 4) * BM;  nOff = (wg & 15) * BN;
    aBase = (size_t)mOff * LDA; qBase = (size_t)nOff * LDQ;
  } else {
    mOff = blockIdx.x * BM;
    nOff = blockIdx.y * BN;
    aBase = (size_t)mOff * LDA;
    qBase = (size_t)nOff * LDQ;
  }

  f32x4 acc[FM][FN] = {};

  for (int kt = 0; kt < KT; ++kt){
    const int k0 = kt * 64;
    bf16x8 ra[CA], rq[CQ];
    if constexpr (!AGL){
      #pragma unroll
      for (int i = 0; i < CA; i++){
        int ch = i * 256 + t;
        int row = ch >> 3, kc = ch & 7, kg = k0 + kc * 8;
        const float* g = (const float*)Ap + aBase + (size_t)row * LDA + kg;
        #pragma unroll
        for (int jj = 0; jj < 8; jj += 4){
          if (kg + jj + 3 < LL){
            float4 v = *(const float4*)(g + jj);
            ra[i][jj] = (bf16)v.x; ra[i][jj+1] = (bf16)v.y;
            ra[i][jj+2] = (bf16)v.z; ra[i][jj+3] = (bf16)v.w;
          } else {
            for (int j = jj; j < jj + 4; j++) ra[i][j] = (bf16)((kg + j) < LL ? g[j] : 0.f);
          }
        }
      }
    }
    if constexpr (!QGL){
      #pragma unroll
      for (int i = 0; i < CQ; i++){
        int ch = i * 256 + t;
        int row = ch >> 3, kc = ch & 7, kg = k0 + kc * 8;
        if constexpr (F32S){
          const float* g = (const float*)Qp + qBase + (size_t)row * LDQ + kg;
          #pragma unroll
          for (int jj = 0; jj < 8; jj += 4){
            if (kg + jj + 3 < LL){
              float4 v = *(const float4*)(g + jj);
              rq[i][jj] = (bf16)v.x; rq[i][jj+1] = (bf16)v.y;
              rq[i][jj+2] = (bf16)v.z; rq[i][jj+3] = (bf16)v.w;
            } else {
              for (int j = jj; j < jj + 4; j++) rq[i][j] = (bf16)((kg + j) < LL ? g[j] : 0.f);
            }
          }
        } else {
          bf16x8 raw = *(const bf16x8*)((const bf16*)Qp + qBase + (size_t)row * LDQ + kg);
          #pragma unroll
          for (int j = 0; j < 8; j++){
            float f = (float)raw[j] * sc[kg + j] + sh[kg + j];
            rq[i][j] = (bf16)fmaxf(f, 0.f);
          }
        }
      }
    }
    __syncthreads();
    if constexpr (AGL){
      #pragma unroll
      for (int c = 0; c < CA; c++){
        int chunk = wid * CA + c;
        int row = chunk * 8 + (lane >> 3);
        gload16((const bf16*)Ap + aBase + (size_t)row * LDA + k0 + sw8, &Ps[chunk * 512]);
      }
    }
    if constexpr (QGL){
      #pragma unroll
      for (int c = 0; c < CQ; c++){
        int chunk = wid * CQ + c;
        int row = chunk * 8 + (lane >> 3);
        gload16((const bf16*)Qp + qBase + (size_t)row * LDQ + k0 + sw8, &Qs[chunk * 512]);
      }
    }
    if constexpr (!AGL){
      #pragma unroll
      for (int i = 0; i < CA; i++){
        int ch = i * 256 + t; int row = ch >> 3, kc = ch & 7;
        *(bf16x8*)&Ps[row * 64 + ((kc ^ (row & 7)) << 3)] = ra[i];
      }
    }
    if constexpr (!QGL){
      #pragma unroll
      for (int i = 0; i < CQ; i++){
        int ch = i * 256 + t; int row = ch >> 3, kc = ch & 7;
        *(bf16x8*)&Qs[row * 64 + ((kc ^ (row & 7)) << 3)] = rq[i];
      }
    }
    __syncthreads();
    #pragma unroll
    for (int ks = 0; ks < 2; ++ks){
      const int kcl = ks * 4 + (lane >> 4);
      bf16x8 af[FM], qf[FN];
      #pragma unroll
      for (int m = 0; m < FM; m++){
        int row = wr * WTM + m * 16 + (lane & 15);
        af[m] = *(const bf16x8*)&Ps[row * 64 + ((kcl ^ (row & 7)) << 3)];
      }
      #pragma unroll
      for (int n = 0; n < FN; n++){
        int row = wc * WTN + n * 16 + (lane & 15);
        qf[n] = *(const bf16x8*)&Qs[row * 64 + ((kcl ^ (row & 7)) << 3)];
      }
      #pragma unroll
      for (int m = 0; m < FM; m++)
        #pragma unroll
        for (int n = 0; n < FN; n++)
          acc[m][n] = __builtin_amdgcn_mfma_f32_16x16x32_bf16(af[m], qf[n], acc[m][n], 0, 0, 0);
    }
  }

  #pragma unroll
  for (int m = 0; m < FM; m++){
    #pragma unroll
    for (int n = 0; n < FN; n++){
      #pragma unroll
      for (int r = 0; r < 4; r++){
        int row = mOff + wr * WTM + m * 16 + (lane >> 4) * 4 + r;
        int col = nOff + wc * WTN + n * 16 + (lane & 15);
        float v = acc[m][n][r];
        if constexpr (CFG == 3 || CFG == 5){
          ((bf16*)Cp)[(size_t)row * 2048 + col] = (bf16)v;
        } else if constexpr (CFG == 2){
          ((float*)Cp)[(size_t)row * P1P + col] = v;
        } else {
          ((float*)Cp)[O_OVAL + (size_t)(col >> 5) * 8192 + (size_t)row * 32 + (col & 31)] = v;
        }
      }
    }
  }
}

__global__ __launch_bounds__(256) void gemm2_k(const void* A, const void* Q, void* C,
                                               const float* sc, const float* sh){ gemm_body<2>(A,Q,C,sc,sh); }
__global__ __launch_bounds__(256) void gemm3_k(const void* A, const void* Q, void* C,
                                               const float* sc, const float* sh){ gemm_body<3>(A,Q,C,sc,sh); }
__global__ __launch_bounds__(256) void gemm4_k(const void* A, const void* Q, void* C,
                                               const float* sc, const float* sh){ gemm_body<4>(A,Q,C,sc,sh); }
__global__ __launch_bounds__(256) void gemm5_k(const void* A, const void* Q, void* C,
                                               const float* sc, const float* sh){ gemm_body<5>(A,Q,C,sc,sh); }

// ======================= launch =======================
extern "C" void kernel_launch(void* const* d_in, const int* in_sizes, int n_in,
                              void* d_out, int out_size, void* d_ws, size_t ws_size,
                              hipStream_t stream){
  const float* x   = (const float*)d_in[0];
  const float* w1p = (const float*)d_in[1];
  const float* gp  = (const float*)d_in[2];
  const float* bp  = (const float*)d_in[3];
  const float* w2p = (const float*)d_in[4];
  const float* w1o = (const float*)d_in[5];
  const float* go  = (const float*)d_in[6];
  const float* bo  = (const float*)d_in[7];
  const float* w2o = (const float*)d_in[8];
  float* out = (float*)d_out;
  char* ws = (char*)d_ws;

  bf16* xcat = (bf16*)(ws + WS_XCAT);
  bf16* v2   = (bf16*)(ws + WS_V2);
  bf16* h2t  = (bf16*)(ws + WS_H2T);
  float* part = (float*)(ws + WS_PART);
  bf16* hT   = (bf16*)(ws + WS_HT);
  float* z   = (float*)(ws + WS_Z);
  bf16* w1b  = (bf16*)(ws + WS_W1B);
  bf16* w2b  = (bf16*)(ws + WS_W2B);
  bf16* w1ob = (bf16*)(ws + WS_W1OB);
  bf16* w2ob = (bf16*)(ws + WS_W2OB);
  float* nrmw = (float*)(ws + WS_NRM);
  float* sc1 = (float*)(ws + WS_SC1);
  float* sh1 = (float*)(ws + WS_SH1);
  float* sc2 = (float*)(ws + WS_SC2);
  float* sh2 = (float*)(ws + WS_SH2);

  cast_k<<<16384, 256, 0, stream>>>(w1p, w1b, HIDN * CIN);
  cast_k<<<2048,  256, 0, stream>>>(w2p, w2b, OUTN * HIDN);
  cast_k<<<16384, 256, 0, stream>>>(w1o, w1ob, HIDN * CIN);
  cast_k<<<2048,  256, 0, stream>>>(w2o, w2ob, OUTN * HIDN);
  zero_b16<<<1536, 256, 0, stream>>>(xcat + (size_t)P1V * 2048, (P1P - P1V) * 2048);
  prep_k<<<2048, 256, 0, stream>>>(x, xcat);

  // MLP1
  gemm1_k<<<400, 512, 0, stream>>>(xcat, w1b, hT);
  stats_part_k<<<256, 256, 0, stream>>>(hT, P1V, 50, part);
  finalize_k<<<8, 256, 0, stream>>>(part, 256, gp, bp, (float)P1V, sc1, sh1);
  gemm2_k<<<dim3(2, 100), 256, 0, stream>>>(w2b, hT, z, sc1, sh1);

  // z_g, channel-norm, softmax
  zg_k<<<64, 256, 0, stream>>>(z, out);
  nrm_k<<<64, 256, 0, stream>>>(z, nrmw);
  softmax_k<<<16384, 64, 0, stream>>>(z, nrmw, out);

  // attention einsum -> MLP2
  gemm5_k<<<512, 256, 0, stream>>>(out + O_ATT, x, v2, nullptr, nullptr);
  gemm3_k<<<256, 256, 0, stream>>>(v2, w1ob, h2t, nullptr, nullptr);
  stats_part_k<<<64, 256, 0, stream>>>(h2t, 2048, 32, part);
  finalize_k<<<8, 256, 0, stream>>>(part, 64, go, bo, 2048.f, sc2, sh2);
  gemm4_k<<<dim3(4, 32), 256, 0, stream>>>(w2ob, h2t, out, sc2, sh2);
}